// Round 13
// baseline (85.989 us; speedup 1.0000x reference)
//
#include <hip/hip_runtime.h>

#define NN 50000
#define NE 800000
#define DD 96
#define NEG 0.01f
#define FN 64        // nodes per fuse4 block
#define NBK 196      // buckets = row>>8 (256 rows each)
#define BCAP 4600    // bucket region capacity (mean 4096, sigma 64; overflow exact)
#define EPA 4096     // edges per binA block
#define NBA 196      // binA blocks
#define OVCAP 65536  // overflow list capacity (normally 0 used)
#define QROW 96      // egoq row stride BYTES: 96 packed int8 (scale separate)

typedef __attribute__((ext_vector_type(8))) short short8v;
typedef __attribute__((ext_vector_type(4))) float f32x4;

static __device__ __forceinline__ float lrelu(float x) {
  return (x >= 0.f) ? x : NEG * x;
}
static __device__ __forceinline__ unsigned short f2bf(float x) {
  unsigned u = __float_as_uint(x);
  u += 0x7fffu + ((u >> 16) & 1u);   // RNE
  return (unsigned short)(u >> 16);
}
static __device__ __forceinline__ float bflo(unsigned u) {
  return __uint_as_float(u << 16);
}
static __device__ __forceinline__ float bfhi(unsigned u) {
  return __uint_as_float(u & 0xFFFF0000u);
}
static __device__ __forceinline__ float sb(unsigned u, int k) {  // signed byte k -> f32
  return (float)((int)(signed char)((u >> (8 * k)) & 0xFF));
}

// ================= fallback (round-1) path =================
__global__ __launch_bounds__(256) void scatter_kernel(
    const float* __restrict__ ego, const float* __restrict__ avals,
    const int* __restrict__ arows, const int* __restrict__ acols,
    float* __restrict__ side)
{
  int t = blockIdx.x * 256 + threadIdx.x;
  int e = t >> 5;
  int lane = t & 31;
  if (e >= NE) return;
  int row = arows[e];
  int col = acols[e];
  float v = avals[e];
  if (lane < 24) {
    const float4* src = (const float4*)(ego + (size_t)col * DD);
    float4 x = src[lane];
    float* dst = side + (size_t)row * DD + lane * 4;
    unsafeAtomicAdd(dst + 0, v * x.x);
    unsafeAtomicAdd(dst + 1, v * x.y);
    unsafeAtomicAdd(dst + 2, v * x.z);
    unsafeAtomicAdd(dst + 3, v * x.w);
  }
}

__global__ __launch_bounds__(192) void fuse_fb_kernel(
    const float* __restrict__ ego, const float* __restrict__ side,
    const float* __restrict__ W1, const float* __restrict__ b1,
    const float* __restrict__ W2, const float* __restrict__ b2,
    float* __restrict__ out)
{
  __shared__ float W1t[DD * DD];
  __shared__ float W2t[DD * DD];
  __shared__ float b1s[DD], b2s[DD];
  __shared__ float xs[192], ys[192];
  int tid = threadIdx.x;
  for (int i = tid; i < DD * DD; i += 192) {
    int j = i / DD, k = i - j * DD;
    W1t[k * DD + j] = W1[i];
    W2t[k * DD + j] = W2[i];
  }
  if (tid < DD) { b1s[tid] = b1[tid]; b2s[tid] = b2[tid]; }
  __syncthreads();
  int nl = tid / DD, j = tid - nl * DD;
  for (int p = blockIdx.x; p < NN / 2; p += gridDim.x) {
    int base = p * 192;
    float e = ego[base + tid], s = side[base + tid];
    xs[tid] = e + s; ys[tid] = e * s;
    __syncthreads();
    float a1 = b1s[j], a2 = b2s[j];
    const float* xr = xs + nl * DD;
    const float* yr = ys + nl * DD;
#pragma unroll 16
    for (int k = 0; k < DD; ++k) {
      a1 += xr[k] * W1t[k * DD + j];
      a2 += yr[k] * W2t[k * DD + j];
    }
    float r = lrelu(a1) + lrelu(a2);
    __syncthreads();
    out[base + tid] = r;
  }
}

// ========== build: binA binning + W->bf16 + ego->int8 (packed, scale split) ==========
#define NB_W   ((DD * DD) / 256)       // 36
#define NB_Q   ((NN + 63) / 64)        // 782 quant blocks (64 rows each)
__global__ __launch_bounds__(256) void build_kernel(
    const int* __restrict__ rows, const int* __restrict__ cols,
    const float* __restrict__ vals,
    int* __restrict__ bptr, int* __restrict__ ovcur,
    int2* __restrict__ ovbuf, int2* __restrict__ buckets,
    const float* __restrict__ W1, const float* __restrict__ W2,
    unsigned short* __restrict__ Wb1, unsigned short* __restrict__ Wb2,
    const float* __restrict__ ego, unsigned char* __restrict__ egoq,
    float* __restrict__ scl)
{
  __shared__ unsigned sw0[EPA];
  __shared__ unsigned sw1[EPA];
  __shared__ unsigned char sbid[EPA];
  __shared__ int bcnt[256], bofs[256], gbase[256], stmp[256];

  int blk = blockIdx.x;
  int tid = threadIdx.x;

  if (blk >= NBA) {
    int b = blk - NBA;
    if (b < NB_W) {
      int i = b * 256 + tid;  // [0, 9216)
      Wb1[i] = f2bf(W1[i]);
      Wb2[i] = f2bf(W2[i]);
    } else {
      // int8 quantization: 64 rows/block, 4 threads/row (24 values each)
      int r_loc = tid >> 2, q = tid & 3;
      int row = (b - NB_W) * 64 + r_loc;
      if (row < NN) {
        float4 f[6];
        const float4* src = (const float4*)(ego + (size_t)row * DD + q * 24);
#pragma unroll
        for (int t = 0; t < 6; ++t) f[t] = src[t];
        float m = 0.f;
#pragma unroll
        for (int t = 0; t < 6; ++t) {
          m = fmaxf(m, fmaxf(fmaxf(fabsf(f[t].x), fabsf(f[t].y)),
                             fmaxf(fabsf(f[t].z), fabsf(f[t].w))));
        }
        m = fmaxf(m, __shfl_xor(m, 1, 64));
        m = fmaxf(m, __shfl_xor(m, 2, 64));
        m = fmaxf(m, 1e-20f);
        float inv = 127.0f / m;
        unsigned* dst = (unsigned*)(egoq + (size_t)row * QROW) + q * 6;
#pragma unroll
        for (int t = 0; t < 6; ++t) {
          int q0 = __float2int_rn(f[t].x * inv);
          int q1 = __float2int_rn(f[t].y * inv);
          int q2 = __float2int_rn(f[t].z * inv);
          int q3 = __float2int_rn(f[t].w * inv);
          dst[t] = (unsigned)(q0 & 255) | ((unsigned)(q1 & 255) << 8) |
                   ((unsigned)(q2 & 255) << 16) | ((unsigned)(q3 & 255) << 24);
        }
        if (q == 0) scl[row] = m * (1.0f / 127.0f);
      }
    }
    return;
  }

  // ---- binA part ----
  int base = blk * EPA;
  int cnt_here = min(EPA, NE - base);

  bcnt[tid] = 0;
  __syncthreads();

  unsigned w0[16], w1[16];
  int bb[16], lp[16];
#pragma unroll
  for (int k = 0; k < 16; ++k) {
    int i = tid + k * 256;
    bb[k] = -1;
    if (i < cnt_here) {
      int e = base + i;
      int r = rows[e], c = cols[e];
      float v = vals[e];
      int b = r >> 8;
      bb[k] = b;
      w0[k] = (unsigned)c | ((unsigned)(r & 255) << 16) | ((unsigned)b << 24);
      w1[k] = (unsigned)f2bf(v);
      lp[k] = atomicAdd(&bcnt[b], 1);
    }
  }
  __syncthreads();

  int v = bcnt[tid];
  stmp[tid] = v;
  __syncthreads();
  for (int off = 1; off < 256; off <<= 1) {
    int add = (tid >= off) ? stmp[tid - off] : 0;
    __syncthreads();
    stmp[tid] += add;
    __syncthreads();
  }
  bofs[tid] = stmp[tid] - v;  // exclusive
  gbase[tid] = (tid < NBK && v > 0) ? atomicAdd(&bptr[tid], v) : 0;
  __syncthreads();

#pragma unroll
  for (int k = 0; k < 16; ++k) {
    if (bb[k] >= 0) {
      int s = bofs[bb[k]] + lp[k];
      sw0[s] = w0[k];
      sw1[s] = w1[k];
      sbid[s] = (unsigned char)bb[k];
    }
  }
  __syncthreads();

  for (int i = tid; i < cnt_here; i += 256) {
    int b = sbid[i];
    int off = i - bofs[b];
    int g = gbase[b] + off;
    int2 ent = make_int2((int)sw0[i], (int)sw1[i]);
    if (g < BCAP) {
      buckets[(size_t)b * BCAP + g] = ent;
    } else {
      int op = atomicAdd(ovcur, 1);
      if (op < OVCAP) ovbuf[op] = ent;
    }
  }
}

// ========== binB: LDS-staged bucket + counting sort -> cv + row_start ==========
__global__ __launch_bounds__(256) void binB_kernel(
    const int2* __restrict__ buckets, const int* __restrict__ bptr,
    const int* __restrict__ ovcur, const int2* __restrict__ ovbuf,
    unsigned* __restrict__ cv, int* __restrict__ row_start)
{
  __shared__ int2 sent[BCAP];
  __shared__ int rcnt[256], rofs[256], rcur[256], stmp[256], sexc[256];
  int b = blockIdx.x, tid = threadIdx.x;

  int bv = (tid < NBK) ? bptr[tid] : 0;
  stmp[tid] = bv;
  __syncthreads();
  for (int off = 1; off < 256; off <<= 1) {
    int add = (tid >= off) ? stmp[tid - off] : 0;
    __syncthreads();
    stmp[tid] += add;
    __syncthreads();
  }
  sexc[tid] = stmp[tid] - bv;
  __syncthreads();
  int cvb = sexc[b];
  int total = bptr[b];
  int nreg = min(total, BCAP);
  int nov = min(*ovcur, OVCAP);
  const int2* reg = buckets + (size_t)b * BCAP;

  rcnt[tid] = 0;
  for (int i = tid; i < nreg; i += 256) sent[i] = reg[i];
  __syncthreads();

  for (int i = tid; i < nreg; i += 256) {
    unsigned w0 = (unsigned)sent[i].x;
    atomicAdd(&rcnt[(w0 >> 16) & 255], 1);
  }
  for (int i = tid; i < nov; i += 256) {
    unsigned w0 = (unsigned)ovbuf[i].x;
    if ((w0 >> 24) == (unsigned)b) atomicAdd(&rcnt[(w0 >> 16) & 255], 1);
  }
  __syncthreads();

  int v = rcnt[tid];
  stmp[tid] = v;
  __syncthreads();
  for (int off = 1; off < 256; off <<= 1) {
    int add = (tid >= off) ? stmp[tid - off] : 0;
    __syncthreads();
    stmp[tid] += add;
    __syncthreads();
  }
  rofs[tid] = stmp[tid] - v;
  rcur[tid] = rofs[tid];
  int grow = b * 256 + tid;
  if (grow <= NN) row_start[grow] = cvb + rofs[tid];
  __syncthreads();

  for (int i = tid; i < nreg; i += 256) {
    unsigned w0 = (unsigned)sent[i].x;
    unsigned w1 = (unsigned)sent[i].y;
    int rl = (w0 >> 16) & 255;
    int p = atomicAdd(&rcur[rl], 1);
    cv[cvb + p] = (w0 & 0xFFFFu) | (w1 << 16);
  }
  for (int i = tid; i < nov; i += 256) {
    unsigned w0 = (unsigned)ovbuf[i].x;
    unsigned w1 = (unsigned)ovbuf[i].y;
    if ((w0 >> 24) == (unsigned)b) {
      int rl = (w0 >> 16) & 255;
      int p = atomicAdd(&rcur[rl], 1);
      cv[cvb + p] = (w0 & 0xFFFFu) | (w1 << 16);
    }
  }
}

// ====== agg: wave/row, quarter-wave gathers, 3-phase pipeline, packed rows ======
__global__ __launch_bounds__(256) void agg_kernel(
    const unsigned char* __restrict__ egoq, const float* __restrict__ scl,
    const int* __restrict__ row_start, const unsigned* __restrict__ cv,
    unsigned* __restrict__ sideb) {
  int wid = threadIdx.x >> 6, lane = threadIdx.x & 63;
  int row = blockIdx.x * 4 + wid;
  if (row >= NN) return;
  int s = row_start[row], e = row_start[row + 1];
  int q = lane >> 4, ql = lane & 15;
  bool act = ql < 12;
  int ql8 = ql * 8;

  float a[4][8];
#pragma unroll
  for (int d = 0; d < 4; ++d)
#pragma unroll
    for (int j = 0; j < 8; ++j) a[d][j] = 0.f;

  for (int base = s; base < e; base += 64) {
    int idx = base + lane;
    unsigned pk = 0;
    if (idx < e) pk = cv[idx];
    int n = min(64, e - base);
    for (int i = 0; i < n; i += 16) {
      unsigned p[4];
#pragma unroll
      for (int d = 0; d < 4; ++d) p[d] = __shfl(pk, i + 4 * d + q, 64);
      uint2 u[4];
      float sc[4];
#pragma unroll
      for (int d = 0; d < 4; ++d) {
        int c = (int)(p[d] & 0xFFFFu);
        const char* rowp = (const char*)egoq + (size_t)c * QROW;
        if (act) {
          u[d] = *(const uint2*)(rowp + ql8);
          sc[d] = scl[c];
        } else {
          u[d] = make_uint2(0u, 0u);
          sc[d] = 0.f;
        }
      }
#pragma unroll
      for (int d = 0; d < 4; ++d) {
        float vs = bfhi(p[d]) * sc[d];
        a[d][0] += vs * sb(u[d].x, 0);
        a[d][1] += vs * sb(u[d].x, 1);
        a[d][2] += vs * sb(u[d].x, 2);
        a[d][3] += vs * sb(u[d].x, 3);
        a[d][4] += vs * sb(u[d].y, 0);
        a[d][5] += vs * sb(u[d].y, 1);
        a[d][6] += vs * sb(u[d].y, 2);
        a[d][7] += vs * sb(u[d].y, 3);
      }
    }
  }

  float r[8];
#pragma unroll
  for (int j = 0; j < 8; ++j) {
    r[j] = (a[0][j] + a[1][j]) + (a[2][j] + a[3][j]);
    r[j] += __shfl_xor(r[j], 16, 64);
    r[j] += __shfl_xor(r[j], 32, 64);
  }
  if (q == 0 && act) {
    uint4 o;
    o.x = (unsigned)f2bf(r[0]) | ((unsigned)f2bf(r[1]) << 16);
    o.y = (unsigned)f2bf(r[2]) | ((unsigned)f2bf(r[3]) << 16);
    o.z = (unsigned)f2bf(r[4]) | ((unsigned)f2bf(r[5]) << 16);
    o.w = (unsigned)f2bf(r[6]) | ((unsigned)f2bf(r[7]) << 16);
    *(uint4*)(sideb + (size_t)row * 48 + ql * 4) = o;
  }
}

// ========== fuse4: bf16 MFMA, DIRECT per-lane global loads (no LDS) ==========
// A-frag mapping: lane l of wave w reads node (blk*FN + w*16 + (l&15)),
// elements kk*32 + (l>>4)*8 .. +8, for kk=0..2 — same elements the old LDS
// version read; now loaded straight from egoq(int8)+scl and sideb(bf16).
__global__ __launch_bounds__(256) void fuse4_kernel(
    const unsigned char* __restrict__ egoq, const float* __restrict__ scl,
    const unsigned* __restrict__ sideb,
    const unsigned short* __restrict__ Wb1, const unsigned short* __restrict__ Wb2,
    const float* __restrict__ b1, const float* __restrict__ b2,
    float* __restrict__ out)
{
  int tid = threadIdx.x;
  int w = tid >> 6, l = tid & 63;
  int lrow = l & 15, lk = l >> 4;
  int nbase = blockIdx.x * FN;
  int node = nbase + w * 16 + lrow;
  bool valid = node < NN;
  int nc = valid ? node : (NN - 1);

  float sc = scl[nc];
  short8v ax[3], ay[3];
#pragma unroll
  for (int kk = 0; kk < 3; ++kk) {
    int kb = kk * 32 + lk * 8;
    uint2 eu = *(const uint2*)(egoq + (size_t)nc * QROW + kb);
    uint4 sv = *(const uint4*)(sideb + (size_t)nc * 48 + kb / 2);
    float ev[8], svf[8];
    ev[0] = sc * sb(eu.x, 0); ev[1] = sc * sb(eu.x, 1);
    ev[2] = sc * sb(eu.x, 2); ev[3] = sc * sb(eu.x, 3);
    ev[4] = sc * sb(eu.y, 0); ev[5] = sc * sb(eu.y, 1);
    ev[6] = sc * sb(eu.y, 2); ev[7] = sc * sb(eu.y, 3);
    svf[0] = bflo(sv.x); svf[1] = bfhi(sv.x);
    svf[2] = bflo(sv.y); svf[3] = bfhi(sv.y);
    svf[4] = bflo(sv.z); svf[5] = bfhi(sv.z);
    svf[6] = bflo(sv.w); svf[7] = bfhi(sv.w);
#pragma unroll
    for (int i = 0; i < 8; ++i) {
      float xv = valid ? (ev[i] + svf[i]) : 0.f;
      float yv = valid ? (ev[i] * svf[i]) : 0.f;
      ax[kk][i] = (short)f2bf(xv);
      ay[kk][i] = (short)f2bf(yv);
    }
  }

  f32x4 acc1[6], acc2[6];
#pragma unroll
  for (int t = 0; t < 6; ++t) {
    acc1[t] = (f32x4){0.f, 0.f, 0.f, 0.f};
    acc2[t] = (f32x4){0.f, 0.f, 0.f, 0.f};
  }

#pragma unroll
  for (int kk = 0; kk < 3; ++kk) {
    int kb = kk * 32 + lk * 8;
#pragma unroll
    for (int t = 0; t < 6; ++t) {
      int j = t * 16 + lrow;
      short8v bw1 = *(const short8v*)(Wb1 + j * DD + kb);
      short8v bw2 = *(const short8v*)(Wb2 + j * DD + kb);
      acc1[t] = __builtin_amdgcn_mfma_f32_16x16x32_bf16(ax[kk], bw1, acc1[t], 0, 0, 0);
      acc2[t] = __builtin_amdgcn_mfma_f32_16x16x32_bf16(ay[kk], bw2, acc2[t], 0, 0, 0);
    }
  }

  int node0 = nbase + w * 16 + lk * 4;
#pragma unroll
  for (int t = 0; t < 6; ++t) {
    int j = t * 16 + lrow;
    float bb1 = b1[j], bb2 = b2[j];
#pragma unroll
    for (int i = 0; i < 4; ++i) {
      int n2 = node0 + i;
      if (n2 < NN)
        out[(size_t)n2 * DD + j] = lrelu(acc1[t][i] + bb1) + lrelu(acc2[t][i] + bb2);
    }
  }
}

// ================= launch =================
extern "C" void kernel_launch(void* const* d_in, const int* in_sizes, int n_in,
                              void* d_out, int out_size, void* d_ws, size_t ws_size,
                              hipStream_t stream) {
  const float* ego   = (const float*)d_in[0];
  const float* avals = (const float*)d_in[1];
  const float* W1    = (const float*)d_in[2];
  const float* b1    = (const float*)d_in[3];
  const float* W2    = (const float*)d_in[4];
  const float* b2    = (const float*)d_in[5];
  const int* arows   = (const int*)d_in[6];
  const int* acols   = (const int*)d_in[7];
  float* out = (float*)d_out;

  size_t off = 0;
  auto bump = [&](size_t bytes) {
    size_t o = off;
    off += (bytes + 1023) & ~(size_t)1023;
    return o;
  };
  char* ws = (char*)d_ws;
  size_t o_rs    = bump((size_t)(NN + 1) * 4);
  size_t o_cv    = bump((size_t)NE * 4);
  size_t o_wb1   = bump((size_t)DD * DD * 2);
  size_t o_wb2   = bump((size_t)DD * DD * 2);
  size_t o_egoq  = bump((size_t)NN * QROW);       // 4.8 MB packed int8 rows
  size_t o_scl   = bump((size_t)NN * 4);          // 200 KB row scales
  size_t o_bptr  = bump((size_t)(NBK + 1) * 4);   // bptr[NBK] + ovcur
  size_t o_ovbuf = bump((size_t)OVCAP * 8);
  size_t o_sideb = bump((size_t)NN * DD * 2);     // 9.6 MB; buckets alias here
  size_t need = off;
  static_assert((size_t)NBK * BCAP * 8 <= (size_t)NN * DD * 2, "buckets fit in sideb");

  if (ws_size >= need) {
    int*  rs    = (int*)(ws + o_rs);
    unsigned* cv = (unsigned*)(ws + o_cv);
    unsigned short* Wb1  = (unsigned short*)(ws + o_wb1);
    unsigned short* Wb2  = (unsigned short*)(ws + o_wb2);
    unsigned char* egoq  = (unsigned char*)(ws + o_egoq);
    float* scl  = (float*)(ws + o_scl);
    int*  bptr  = (int*)(ws + o_bptr);
    int*  ovcur = bptr + NBK;
    int2* ovbuf = (int2*)(ws + o_ovbuf);
    unsigned* sideb = (unsigned*)(ws + o_sideb);
    int2* buckets = (int2*)(ws + o_sideb);

    hipMemsetAsync(bptr, 0, (size_t)(NBK + 1) * 4, stream);
    build_kernel<<<NBA + NB_W + NB_Q, 256, 0, stream>>>(
        arows, acols, avals, bptr, ovcur, ovbuf, buckets,
        W1, W2, Wb1, Wb2, ego, egoq, scl);
    binB_kernel<<<NBK, 256, 0, stream>>>(buckets, bptr, ovcur, ovbuf, cv, rs);
    agg_kernel<<<(NN + 3) / 4, 256, 0, stream>>>(egoq, scl, rs, cv, sideb);
    fuse4_kernel<<<(NN + FN - 1) / FN, 256, 0, stream>>>(
        egoq, scl, sideb, Wb1, Wb2, b1, b2, out);
  } else {
    size_t side_bytes = (size_t)NN * DD * sizeof(float);
    float* side = (ws_size >= side_bytes) ? (float*)d_ws : out;
    hipMemsetAsync(side, 0, side_bytes, stream);
    long long nthreads = (long long)NE * 32;
    int blocks = (int)((nthreads + 255) / 256);
    scatter_kernel<<<blocks, 256, 0, stream>>>(ego, avals, arows, acols, side);
    fuse_fb_kernel<<<1024, 192, 0, stream>>>(ego, side, W1, b1, W2, b2, out);
  }
}